// Round 6
// baseline (298.921 us; speedup 1.0000x reference)
//
#include <hip/hip_runtime.h>
#include <math.h>

#define BATCH 16384
#define OUTF  1024
#define INF   1024
#define KPROJ 256
#define MTOT  (BATCH + OUTF)   // 17408

#define NZ_THRESH 0.15f        // ~4 sigma of f16 dot error (sigma ~0.037)
#define QCAP 49152u            // fixup queue capacity (expected ~16.5k items)

typedef unsigned int       u32;
typedef unsigned long long u64;
typedef unsigned short     u16;
typedef _Float16           f16;
typedef __attribute__((ext_vector_type(8))) _Float16 f16x8;
typedef __attribute__((ext_vector_type(4))) float    f32x4;

#define SCHED0() __builtin_amdgcn_sched_barrier(0)

// ---------------------------------------------------------------------------
// prep_p: P (256 x 1024) fp32 -> f16 in MFMA FRAGMENT ORDER, coalesced.
// Fragment f = (kt*16 + j)*2 + ks holds, for lane = lq*16+l15, the 8 f16
// elements  B[col = j*16+l15][k = kt*64 + ks*32 + lq*8 .. +7].
// ---------------------------------------------------------------------------
__global__ __launch_bounds__(256) void prep_p(const float* __restrict__ P,
                                              f16* __restrict__ Bf) {
    __shared__ f16 tile[16][1024];     // 32 KB
    const int j = blockIdx.x;          // 0..15 (col block)
    const int t = threadIdx.x;
#pragma unroll
    for (int r = 0; r < 16; ++r) {
        const float4 f = ((const float4*)(P + (size_t)(j * 16 + r) * INF))[t];
        f16* d = &tile[r][t * 4];
        d[0] = (f16)f.x; d[1] = (f16)f.y; d[2] = (f16)f.z; d[3] = (f16)f.w;
    }
    __syncthreads();
    const int lane = t & 63, fo = t >> 6;
    const int lq = lane >> 4, l15 = lane & 15;
#pragma unroll
    for (int g = 0; g < 8; ++g) {
        const int f  = g * 4 + fo;         // 0..31 = kt*2 + ks
        const int kt = f >> 1, ks = f & 1;
        f16x8 h = *(const f16x8*)&tile[l15][kt * 64 + ks * 32 + lq * 8];
        *(f16x8*)(Bf + (size_t)((((kt * 16 + j) * 2 + ks) * 64) + lane) * 8) = h;
    }
}

// ---------------------------------------------------------------------------
// K-split sign GEMM (R4 core) with the fp64 fixup EXTRACTED to a separate
// kernel.  Epilogue now only ballot-compacts flagged near-zero dots into a
// global work queue (one atomicAdd per wave per ballot round, rare) and
// packs the optimistic f16 sign.  launch_bounds(256,4): 4 blocks/CU
// resident (VGPR was 112 <= 128), doubling TLP vs R4.
// ---------------------------------------------------------------------------
__global__ __launch_bounds__(256, 4) void gemm_signs(const float* __restrict__ X,
                                                     const float* __restrict__ W,
                                                     const f16* __restrict__ Bf,
                                                     u64* __restrict__ cx,
                                                     u64* __restrict__ cw,
                                                     float* __restrict__ xn,
                                                     float* __restrict__ wn,
                                                     u32* __restrict__ cnt,
                                                     u32* __restrict__ queue) {
    __shared__ f32x4 red[2][16][64];    // 32 KB reduction buffer
    __shared__ float nsq[4][16];
    __shared__ u16 sw[16][16];

    const int t    = threadIdx.x;
    const int wid  = t >> 6, lane = t & 63;
    const int l4   = lane >> 4, l15 = lane & 15;
    const int row0 = blockIdx.x * 16;
    const int kb   = ((wid + blockIdx.x) & 3) * 4;   // K-quarter rotation
    const int roff = (blockIdx.x * 5) & 15;          // column rotation

    const float* Asrc = (row0 < BATCH) ? X + (size_t)row0 * INF
                                       : W + (size_t)(row0 - BATCH) * INF;
    const float* aPtr = Asrc + (size_t)l15 * INF + l4 * 8;

    // ---- A preload: this wave's 4 K-tiles, fp32 -> f16 fragments ----
    f16x8 af[8];            // af[2i]: ks=0 of tile kb+i, af[2i+1]: ks=1
    float ssq = 0.0f;
#pragma unroll
    for (int i = 0; i < 4; ++i) {
        const float* p = aPtr + (kb + i) * 64;
        float4 q0 = *(const float4*)(p);
        float4 q1 = *(const float4*)(p + 4);
        float4 q2 = *(const float4*)(p + 32);
        float4 q3 = *(const float4*)(p + 36);
        ssq += q0.x * q0.x + q0.y * q0.y + q0.z * q0.z + q0.w * q0.w +
               q1.x * q1.x + q1.y * q1.y + q1.z * q1.z + q1.w * q1.w +
               q2.x * q2.x + q2.y * q2.y + q2.z * q2.z + q2.w * q2.w +
               q3.x * q3.x + q3.y * q3.y + q3.z * q3.z + q3.w * q3.w;
        f16x8 a0, a1;
        a0[0] = (f16)q0.x; a0[1] = (f16)q0.y; a0[2] = (f16)q0.z; a0[3] = (f16)q0.w;
        a0[4] = (f16)q1.x; a0[5] = (f16)q1.y; a0[6] = (f16)q1.z; a0[7] = (f16)q1.w;
        a1[0] = (f16)q2.x; a1[1] = (f16)q2.y; a1[2] = (f16)q2.z; a1[3] = (f16)q2.w;
        a1[4] = (f16)q3.x; a1[5] = (f16)q3.y; a1[6] = (f16)q3.z; a1[7] = (f16)q3.w;
        af[2 * i]     = a0;
        af[2 * i + 1] = a1;
    }

    // f16-element offsets of each acc slot's column fragment pair
    int joff[16];
#pragma unroll
    for (int s = 0; s < 16; ++s) joff[s] = ((s + roff) & 15) * 1024;

    f32x4 acc[16] = {};
    const f16* bq = Bf + lane * 8;

    f16x8 bA0, bA1, bA2, bA3, bA4, bA5, bA6, bA7;
    f16x8 bB0, bB1, bB2, bB3, bB4, bB5, bB6, bB7;
    f16x8 bC0, bC1, bC2, bC3, bC4, bC5, bC6, bC7;

#define BLOAD(BUF, G)                                                         \
    {                                                                         \
        const f16* bt_ = bq + (size_t)(kb + ((G) >> 2)) * 16384;              \
        BUF##0 = *(const f16x8*)(bt_ + joff[((G) & 3) * 4 + 0]);              \
        BUF##1 = *(const f16x8*)(bt_ + joff[((G) & 3) * 4 + 0] + 512);        \
        BUF##2 = *(const f16x8*)(bt_ + joff[((G) & 3) * 4 + 1]);              \
        BUF##3 = *(const f16x8*)(bt_ + joff[((G) & 3) * 4 + 1] + 512);        \
        BUF##4 = *(const f16x8*)(bt_ + joff[((G) & 3) * 4 + 2]);              \
        BUF##5 = *(const f16x8*)(bt_ + joff[((G) & 3) * 4 + 2] + 512);        \
        BUF##6 = *(const f16x8*)(bt_ + joff[((G) & 3) * 4 + 3]);              \
        BUF##7 = *(const f16x8*)(bt_ + joff[((G) & 3) * 4 + 3] + 512);        \
    }

#define BMFMA(BUF, G)                                                         \
    {                                                                         \
        acc[((G) & 3) * 4 + 0] = __builtin_amdgcn_mfma_f32_16x16x32_f16(      \
            af[2 * ((G) >> 2)],     BUF##0, acc[((G) & 3) * 4 + 0], 0, 0, 0); \
        acc[((G) & 3) * 4 + 0] = __builtin_amdgcn_mfma_f32_16x16x32_f16(      \
            af[2 * ((G) >> 2) + 1], BUF##1, acc[((G) & 3) * 4 + 0], 0, 0, 0); \
        acc[((G) & 3) * 4 + 1] = __builtin_amdgcn_mfma_f32_16x16x32_f16(      \
            af[2 * ((G) >> 2)],     BUF##2, acc[((G) & 3) * 4 + 1], 0, 0, 0); \
        acc[((G) & 3) * 4 + 1] = __builtin_amdgcn_mfma_f32_16x16x32_f16(      \
            af[2 * ((G) >> 2) + 1], BUF##3, acc[((G) & 3) * 4 + 1], 0, 0, 0); \
        acc[((G) & 3) * 4 + 2] = __builtin_amdgcn_mfma_f32_16x16x32_f16(      \
            af[2 * ((G) >> 2)],     BUF##4, acc[((G) & 3) * 4 + 2], 0, 0, 0); \
        acc[((G) & 3) * 4 + 2] = __builtin_amdgcn_mfma_f32_16x16x32_f16(      \
            af[2 * ((G) >> 2) + 1], BUF##5, acc[((G) & 3) * 4 + 2], 0, 0, 0); \
        acc[((G) & 3) * 4 + 3] = __builtin_amdgcn_mfma_f32_16x16x32_f16(      \
            af[2 * ((G) >> 2)],     BUF##6, acc[((G) & 3) * 4 + 3], 0, 0, 0); \
        acc[((G) & 3) * 4 + 3] = __builtin_amdgcn_mfma_f32_16x16x32_f16(      \
            af[2 * ((G) >> 2) + 1], BUF##7, acc[((G) & 3) * 4 + 3], 0, 0, 0); \
    }

#define STEPL(BUF, G, VM, GN)                                                 \
    asm volatile("s_waitcnt vmcnt(" VM ")" ::: "memory");                     \
    SCHED0();                                                                 \
    BMFMA(BUF, G);                                                            \
    BLOAD(BUF, GN);                                                           \
    SCHED0();

#define STEPN(BUF, G, VM)                                                     \
    asm volatile("s_waitcnt vmcnt(" VM ")" ::: "memory");                     \
    SCHED0();                                                                 \
    BMFMA(BUF, G);                                                            \
    SCHED0();

    // prologue: 3 batches in flight
    BLOAD(bA, 0);
    BLOAD(bB, 1);
    BLOAD(bC, 2);
    STEPL(bA, 0,  "16", 3);
    STEPL(bB, 1,  "16", 4);
    STEPL(bC, 2,  "16", 5);
    STEPL(bA, 3,  "16", 6);
    STEPL(bB, 4,  "16", 7);
    STEPL(bC, 5,  "16", 8);
    STEPL(bA, 6,  "16", 9);
    STEPL(bB, 7,  "16", 10);
    STEPL(bC, 8,  "16", 11);
    STEPL(bA, 9,  "16", 12);
    STEPL(bB, 10, "16", 13);
    STEPL(bC, 11, "16", 14);
    STEPL(bA, 12, "16", 15);
    STEPN(bB, 13, "16");
    STEPN(bC, 14, "8");
    STEPN(bA, 15, "0");

    // ---- partial row norms (rows lane-private: row = row0 + l15) ----
    ssq += __shfl_xor(ssq, 16, 64);
    ssq += __shfl_xor(ssq, 32, 64);
    if (lane < 16) nsq[wid][l15] = ssq;

    // ---- 2-round LDS reduction of the 4 partial acc sets ----
    if (wid == 1)
#pragma unroll
        for (int j = 0; j < 16; ++j) red[0][j][lane] = acc[j];
    if (wid == 3)
#pragma unroll
        for (int j = 0; j < 16; ++j) red[1][j][lane] = acc[j];
    __syncthreads();
    if (wid == 0)
#pragma unroll
        for (int j = 0; j < 16; ++j) acc[j] += red[0][j][lane];
    if (wid == 2)
#pragma unroll
        for (int j = 0; j < 16; ++j) {
            acc[j] += red[1][j][lane];
            red[1][j][lane] = acc[j];
        }
    if (wid == 1 && lane < 16) {     // finalize norms on an idle wave
        const float s = nsq[0][lane] + nsq[1][lane] + nsq[2][lane] + nsq[3][lane];
        const float n = sqrtf(s) + 1.1920929e-07f;
        const int grow = row0 + lane;
        if (grow < BATCH) xn[grow] = n; else wn[grow - BATCH] = n;
    }
    __syncthreads();
    if (wid == 0)
#pragma unroll
        for (int j = 0; j < 16; ++j) {
            acc[j] += red[1][j][lane];
            red[0][j][lane] = acc[j];
        }
    __syncthreads();

    // ---- distributed epilogue: wave w owns acc slots s = w*4 .. w*4+3,
    //      holding column-block jc = (s + roff) & 15.  Near-zero dots are
    //      ballot-compacted into the global fixup queue; bit packed
    //      optimistically from the f16 sign. ----
    f32x4 facc[4];
#pragma unroll
    for (int jj = 0; jj < 4; ++jj) facc[jj] = red[0][wid * 4 + jj][lane];

#pragma unroll
    for (int jj = 0; jj < 4; ++jj) {
        const int j = (wid * 4 + jj + roff) & 15;    // actual column block
#pragma unroll
        for (int q = 0; q < 4; ++q) {
            const float v = facc[jj][q];
            const int bit = (v >= 0.0f) ? 1 : 0;
            const u64 fl = __ballot(fabsf(v) < NZ_THRESH);
            if (fl) {
                u32 base;
                if (lane == 0) base = atomicAdd(cnt, (u32)__popcll(fl));
                base = (u32)__shfl((int)base, 0, 64);
                if ((fl >> lane) & 1ull) {
                    const u32 rank = (u32)__popcll(fl & ((1ull << lane) - 1ull));
                    const u32 idx  = base + rank;
                    const u32 grow = (u32)(row0 + l4 * 4 + q);
                    const u32 col  = (u32)(j * 16 + l15);
                    if (idx < QCAP) queue[idx] = (grow << 9) | (col << 1) | (u32)bit;
                }
            }
            const u64 b = __ballot(bit != 0);
            if (l15 == 0)
                sw[l4 * 4 + q][j] = (u16)(b >> (l4 * 16));
        }
    }
    __syncthreads();
    if (t < 64) {
        const int r = t >> 2, w = t & 3;
        const u64 val = *(const u64*)&sw[r][w * 4];
        const int grow = row0 + r;
        if (grow < BATCH) cx[(size_t)grow * 4 + w] = val;
        else              cw[(size_t)(grow - BATCH) * 4 + w] = val;
    }
}

// ---------------------------------------------------------------------------
// fixup_k: whole-wave fp64 re-dot of each queued near-zero item; XOR the
// packed sign bit when the fp64 sign disagrees with the optimistic f16 bit.
// ---------------------------------------------------------------------------
__global__ __launch_bounds__(256) void fixup_k(const float* __restrict__ X,
                                               const float* __restrict__ W,
                                               const float* __restrict__ Pf,
                                               u64* __restrict__ cx,
                                               u64* __restrict__ cw,
                                               const u32* __restrict__ cnt,
                                               const u32* __restrict__ queue) {
    const int lane = threadIdx.x & 63;
    const u32 gw = blockIdx.x * 4 + (threadIdx.x >> 6);
    const u32 nw = gridDim.x * 4;
    const u32 n0 = *cnt;
    const u32 n  = (n0 < QCAP) ? n0 : QCAP;
    for (u32 it = gw; it < n; it += nw) {
        const u32 v    = queue[it];
        const u32 row  = v >> 9;
        const u32 col  = (v >> 1) & 255u;
        const u32 obit = v & 1u;
        const float* xr = ((row < BATCH) ? X + (size_t)row * INF
                                         : W + (size_t)(row - BATCH) * INF) + lane * 16;
        const float* pr = Pf + (size_t)col * INF + lane * 16;
        double s = 0.0;
#pragma unroll
        for (int c4 = 0; c4 < 4; ++c4) {
            float4 xa = *(const float4*)(xr + c4 * 4);
            float4 pa = *(const float4*)(pr + c4 * 4);
            s += (double)xa.x * pa.x + (double)xa.y * pa.y +
                 (double)xa.z * pa.z + (double)xa.w * pa.w;
        }
#pragma unroll
        for (int off = 32; off; off >>= 1) s += __shfl_xor(s, off, 64);
        const u32 nbit = (s >= 0.0) ? 1u : 0u;
        if (lane == 0 && nbit != obit) {
            u64* wptr = (row < BATCH) ? &cx[(size_t)row * 4 + (col >> 6)]
                                      : &cw[(size_t)(row - BATCH) * 4 + (col >> 6)];
            atomicXor(wptr, 1ull << (col & 63));
        }
    }
}

// ---------------------------------------------------------------------------
// out[b][m] = xn[b] * wn[m] * cos(pi * popc / 256)
// ---------------------------------------------------------------------------
__global__ __launch_bounds__(256) void popc_out(const u64* __restrict__ cx,
                                                const u64* __restrict__ cw,
                                                const float* __restrict__ xn,
                                                const float* __restrict__ wn,
                                                float* __restrict__ out) {
    __shared__ float lut[257];
    __shared__ u64 cxs[64][4];
    __shared__ float xns[64];
    const int t = threadIdx.x;

    lut[t] = (float)cos((double)t * (3.14159265358979323846 / 256.0));
    if (t == 0) lut[256] = -1.0f;

    const int r0 = blockIdx.x * 64;
    cxs[t >> 2][t & 3] = cx[(size_t)r0 * 4 + t];
    if (t < 64) xns[t] = xn[r0 + t];

    const ulonglong4* cwv4 = (const ulonglong4*)cw;
    ulonglong4 c0 = cwv4[4 * t + 0];
    ulonglong4 c1 = cwv4[4 * t + 1];
    ulonglong4 c2 = cwv4[4 * t + 2];
    ulonglong4 c3 = cwv4[4 * t + 3];
    float4 wnr = ((const float4*)wn)[t];

    __syncthreads();

    float4* outv = (float4*)out;
    const size_t obase = (size_t)r0 * (OUTF / 4) + t;
#pragma unroll 4
    for (int r = 0; r < 64; ++r) {
        const u64 a0 = cxs[r][0], a1 = cxs[r][1], a2 = cxs[r][2], a3 = cxs[r][3];
        const float sx = xns[r];
        float4 o;
        o.x = sx * wnr.x * lut[__popcll(a0 ^ c0.x) + __popcll(a1 ^ c0.y) +
                               __popcll(a2 ^ c0.z) + __popcll(a3 ^ c0.w)];
        o.y = sx * wnr.y * lut[__popcll(a0 ^ c1.x) + __popcll(a1 ^ c1.y) +
                               __popcll(a2 ^ c1.z) + __popcll(a3 ^ c1.w)];
        o.z = sx * wnr.z * lut[__popcll(a0 ^ c2.x) + __popcll(a1 ^ c2.y) +
                               __popcll(a2 ^ c2.z) + __popcll(a3 ^ c2.w)];
        o.w = sx * wnr.w * lut[__popcll(a0 ^ c3.x) + __popcll(a1 ^ c3.y) +
                               __popcll(a2 ^ c3.z) + __popcll(a3 ^ c3.w)];
        outv[obase + (size_t)r * (OUTF / 4)] = o;
    }
}

extern "C" void kernel_launch(void* const* d_in, const int* in_sizes, int n_in,
                              void* d_out, int out_size, void* d_ws, size_t ws_size,
                              hipStream_t stream) {
    const float* x = (const float*)d_in[0];
    const float* w = (const float*)d_in[1];
    const float* P = (const float*)d_in[2];
    float* out = (float*)d_out;

    char* ws = (char*)d_ws;
    f16*  Bp = (f16*)ws;                         // +0        (524288 B)
    u64*  cx = (u64*)(ws + 524288);              // +524288   (524288 B)
    u64*  cw = (u64*)(ws + 1048576);             // +1048576  (32768 B)
    float* xn = (float*)(ws + 1081344);          // +1081344  (65536 B)
    float* wn = (float*)(ws + 1146880);          // +1146880  (4096 B)
    u32*  cnt = (u32*)(ws + 1150976);            // +1150976  (256 B, 4 used)
    u32*  qu  = (u32*)(ws + 1151232);            // +1151232  (196608 B)

    prep_p<<<16, 256, 0, stream>>>(P, Bp);
    hipMemsetAsync(cnt, 0, 4, stream);

    gemm_signs<<<MTOT / 16, 256, 0, stream>>>(x, w, Bp, cx, cw, xn, wn, cnt, qu);

    fixup_k<<<512, 256, 0, stream>>>(x, w, P, cx, cw, cnt, qu);

    popc_out<<<BATCH / 64, 256, 0, stream>>>(cx, cw, xn, wn, out);
}

// Round 7
// 228.721 us; speedup vs baseline: 1.3069x; 1.3069x over previous
//
#include <hip/hip_runtime.h>
#include <math.h>

#define BATCH 16384
#define OUTF  1024
#define INF   1024
#define KPROJ 256
#define MTOT  (BATCH + OUTF)   // 17408

#define NZ_THRESH 0.15f        // ~6.8 sigma of f16 dot error (sigma ~0.022)
#define QCAP 49152u            // fixup queue capacity (expected ~16.5k items)

typedef unsigned int       u32;
typedef unsigned long long u64;
typedef unsigned short     u16;
typedef _Float16           f16;
typedef __attribute__((ext_vector_type(8))) _Float16 f16x8;
typedef __attribute__((ext_vector_type(4))) float    f32x4;

#define SCHED0() __builtin_amdgcn_sched_barrier(0)

// ---------------------------------------------------------------------------
// prep_p: P (256 x 1024) fp32 -> f16 in MFMA FRAGMENT ORDER, coalesced.
// Fragment f = (kt*16 + j)*2 + ks holds, for lane = lq*16+l15, the 8 f16
// elements  B[col = j*16+l15][k = kt*64 + ks*32 + lq*8 .. +7].
// ---------------------------------------------------------------------------
__global__ __launch_bounds__(256) void prep_p(const float* __restrict__ P,
                                              f16* __restrict__ Bf) {
    __shared__ f16 tile[16][1024];     // 32 KB
    const int j = blockIdx.x;          // 0..15 (col block)
    const int t = threadIdx.x;
#pragma unroll
    for (int r = 0; r < 16; ++r) {
        const float4 f = ((const float4*)(P + (size_t)(j * 16 + r) * INF))[t];
        f16* d = &tile[r][t * 4];
        d[0] = (f16)f.x; d[1] = (f16)f.y; d[2] = (f16)f.z; d[3] = (f16)f.w;
    }
    __syncthreads();
    const int lane = t & 63, fo = t >> 6;
    const int lq = lane >> 4, l15 = lane & 15;
#pragma unroll
    for (int g = 0; g < 8; ++g) {
        const int f  = g * 4 + fo;         // 0..31 = kt*2 + ks
        const int kt = f >> 1, ks = f & 1;
        f16x8 h = *(const f16x8*)&tile[l15][kt * 64 + ks * 32 + lq * 8];
        *(f16x8*)(Bf + (size_t)((((kt * 16 + j) * 2 + ks) * 64) + lane) * 8) = h;
    }
}

// ---------------------------------------------------------------------------
// K-split sign GEMM: R4 core EXACTLY (launch_bounds(256,2) -> no spill,
// VGPR ~112; normal cached loads; K-quarter + column rotation; 3 rotating
// register buffer sets, counted vmcnt(16), 24 B-loads in flight), with the
// fp64 fixup EXTRACTED: epilogue ballot-compacts flagged near-zero dots
// into a global queue (rare; one atomicAdd per wave per event-round) and
// packs the optimistic f16 sign.  A-preload issues all 16 loads before any
// conversion (R4 exposed ~4x HBM latency by converting per group of 4).
// ---------------------------------------------------------------------------
__global__ __launch_bounds__(256, 2) void gemm_signs(const float* __restrict__ X,
                                                     const float* __restrict__ W,
                                                     const f16* __restrict__ Bf,
                                                     u64* __restrict__ cx,
                                                     u64* __restrict__ cw,
                                                     float* __restrict__ xn,
                                                     float* __restrict__ wn,
                                                     u32* __restrict__ cnt,
                                                     u32* __restrict__ queue) {
    __shared__ f32x4 red[2][16][64];    // 32 KB reduction buffer
    __shared__ float nsq[4][16];
    __shared__ u16 sw[16][16];

    const int t    = threadIdx.x;
    const int wid  = t >> 6, lane = t & 63;
    const int l4   = lane >> 4, l15 = lane & 15;
    const int row0 = blockIdx.x * 16;
    const int kb   = ((wid + blockIdx.x) & 3) * 4;   // K-quarter rotation
    const int roff = (blockIdx.x * 5) & 15;          // column rotation

    const float* Asrc = (row0 < BATCH) ? X + (size_t)row0 * INF
                                       : W + (size_t)(row0 - BATCH) * INF;
    const float* aPtr = Asrc + (size_t)l15 * INF + l4 * 8;

    // ---- A preload: ALL 16 loads issued first, then convert ----
    float4 aq[16];
#pragma unroll
    for (int i = 0; i < 4; ++i) {
        const float* p = aPtr + (kb + i) * 64;
        aq[4 * i + 0] = *(const float4*)(p);
        aq[4 * i + 1] = *(const float4*)(p + 4);
        aq[4 * i + 2] = *(const float4*)(p + 32);
        aq[4 * i + 3] = *(const float4*)(p + 36);
    }
    f16x8 af[8];            // af[2i]: ks=0 of tile kb+i, af[2i+1]: ks=1
    float ssq = 0.0f;
#pragma unroll
    for (int i = 0; i < 4; ++i) {
        const float4 q0 = aq[4 * i + 0], q1 = aq[4 * i + 1];
        const float4 q2 = aq[4 * i + 2], q3 = aq[4 * i + 3];
        ssq += q0.x * q0.x + q0.y * q0.y + q0.z * q0.z + q0.w * q0.w +
               q1.x * q1.x + q1.y * q1.y + q1.z * q1.z + q1.w * q1.w +
               q2.x * q2.x + q2.y * q2.y + q2.z * q2.z + q2.w * q2.w +
               q3.x * q3.x + q3.y * q3.y + q3.z * q3.z + q3.w * q3.w;
        f16x8 a0, a1;
        a0[0] = (f16)q0.x; a0[1] = (f16)q0.y; a0[2] = (f16)q0.z; a0[3] = (f16)q0.w;
        a0[4] = (f16)q1.x; a0[5] = (f16)q1.y; a0[6] = (f16)q1.z; a0[7] = (f16)q1.w;
        a1[0] = (f16)q2.x; a1[1] = (f16)q2.y; a1[2] = (f16)q2.z; a1[3] = (f16)q2.w;
        a1[4] = (f16)q3.x; a1[5] = (f16)q3.y; a1[6] = (f16)q3.z; a1[7] = (f16)q3.w;
        af[2 * i]     = a0;
        af[2 * i + 1] = a1;
    }

    // f16-element offsets of each acc slot's column fragment pair
    int joff[16];
#pragma unroll
    for (int s = 0; s < 16; ++s) joff[s] = ((s + roff) & 15) * 1024;

    f32x4 acc[16] = {};
    const f16* bq = Bf + lane * 8;

    f16x8 bA0, bA1, bA2, bA3, bA4, bA5, bA6, bA7;
    f16x8 bB0, bB1, bB2, bB3, bB4, bB5, bB6, bB7;
    f16x8 bC0, bC1, bC2, bC3, bC4, bC5, bC6, bC7;

#define BLOAD(BUF, G)                                                         \
    {                                                                         \
        const f16* bt_ = bq + (size_t)(kb + ((G) >> 2)) * 16384;              \
        BUF##0 = *(const f16x8*)(bt_ + joff[((G) & 3) * 4 + 0]);              \
        BUF##1 = *(const f16x8*)(bt_ + joff[((G) & 3) * 4 + 0] + 512);        \
        BUF##2 = *(const f16x8*)(bt_ + joff[((G) & 3) * 4 + 1]);              \
        BUF##3 = *(const f16x8*)(bt_ + joff[((G) & 3) * 4 + 1] + 512);        \
        BUF##4 = *(const f16x8*)(bt_ + joff[((G) & 3) * 4 + 2]);              \
        BUF##5 = *(const f16x8*)(bt_ + joff[((G) & 3) * 4 + 2] + 512);        \
        BUF##6 = *(const f16x8*)(bt_ + joff[((G) & 3) * 4 + 3]);              \
        BUF##7 = *(const f16x8*)(bt_ + joff[((G) & 3) * 4 + 3] + 512);        \
    }

#define BMFMA(BUF, G)                                                         \
    {                                                                         \
        acc[((G) & 3) * 4 + 0] = __builtin_amdgcn_mfma_f32_16x16x32_f16(      \
            af[2 * ((G) >> 2)],     BUF##0, acc[((G) & 3) * 4 + 0], 0, 0, 0); \
        acc[((G) & 3) * 4 + 0] = __builtin_amdgcn_mfma_f32_16x16x32_f16(      \
            af[2 * ((G) >> 2) + 1], BUF##1, acc[((G) & 3) * 4 + 0], 0, 0, 0); \
        acc[((G) & 3) * 4 + 1] = __builtin_amdgcn_mfma_f32_16x16x32_f16(      \
            af[2 * ((G) >> 2)],     BUF##2, acc[((G) & 3) * 4 + 1], 0, 0, 0); \
        acc[((G) & 3) * 4 + 1] = __builtin_amdgcn_mfma_f32_16x16x32_f16(      \
            af[2 * ((G) >> 2) + 1], BUF##3, acc[((G) & 3) * 4 + 1], 0, 0, 0); \
        acc[((G) & 3) * 4 + 2] = __builtin_amdgcn_mfma_f32_16x16x32_f16(      \
            af[2 * ((G) >> 2)],     BUF##4, acc[((G) & 3) * 4 + 2], 0, 0, 0); \
        acc[((G) & 3) * 4 + 2] = __builtin_amdgcn_mfma_f32_16x16x32_f16(      \
            af[2 * ((G) >> 2) + 1], BUF##5, acc[((G) & 3) * 4 + 2], 0, 0, 0); \
        acc[((G) & 3) * 4 + 3] = __builtin_amdgcn_mfma_f32_16x16x32_f16(      \
            af[2 * ((G) >> 2)],     BUF##6, acc[((G) & 3) * 4 + 3], 0, 0, 0); \
        acc[((G) & 3) * 4 + 3] = __builtin_amdgcn_mfma_f32_16x16x32_f16(      \
            af[2 * ((G) >> 2) + 1], BUF##7, acc[((G) & 3) * 4 + 3], 0, 0, 0); \
    }

#define STEPL(BUF, G, VM, GN)                                                 \
    asm volatile("s_waitcnt vmcnt(" VM ")" ::: "memory");                     \
    SCHED0();                                                                 \
    BMFMA(BUF, G);                                                            \
    BLOAD(BUF, GN);                                                           \
    SCHED0();

#define STEPN(BUF, G, VM)                                                     \
    asm volatile("s_waitcnt vmcnt(" VM ")" ::: "memory");                     \
    SCHED0();                                                                 \
    BMFMA(BUF, G);                                                            \
    SCHED0();

    // prologue: 3 batches in flight
    BLOAD(bA, 0);
    BLOAD(bB, 1);
    BLOAD(bC, 2);
    STEPL(bA, 0,  "16", 3);
    STEPL(bB, 1,  "16", 4);
    STEPL(bC, 2,  "16", 5);
    STEPL(bA, 3,  "16", 6);
    STEPL(bB, 4,  "16", 7);
    STEPL(bC, 5,  "16", 8);
    STEPL(bA, 6,  "16", 9);
    STEPL(bB, 7,  "16", 10);
    STEPL(bC, 8,  "16", 11);
    STEPL(bA, 9,  "16", 12);
    STEPL(bB, 10, "16", 13);
    STEPL(bC, 11, "16", 14);
    STEPL(bA, 12, "16", 15);
    STEPN(bB, 13, "16");
    STEPN(bC, 14, "8");
    STEPN(bA, 15, "0");

    // ---- partial row norms (rows lane-private: row = row0 + l15) ----
    ssq += __shfl_xor(ssq, 16, 64);
    ssq += __shfl_xor(ssq, 32, 64);
    if (lane < 16) nsq[wid][l15] = ssq;

    // ---- 2-round LDS reduction of the 4 partial acc sets ----
    if (wid == 1)
#pragma unroll
        for (int j = 0; j < 16; ++j) red[0][j][lane] = acc[j];
    if (wid == 3)
#pragma unroll
        for (int j = 0; j < 16; ++j) red[1][j][lane] = acc[j];
    __syncthreads();
    if (wid == 0)
#pragma unroll
        for (int j = 0; j < 16; ++j) acc[j] += red[0][j][lane];
    if (wid == 2)
#pragma unroll
        for (int j = 0; j < 16; ++j) {
            acc[j] += red[1][j][lane];
            red[1][j][lane] = acc[j];
        }
    if (wid == 1 && lane < 16) {     // finalize norms on an idle wave
        const float s = nsq[0][lane] + nsq[1][lane] + nsq[2][lane] + nsq[3][lane];
        const float n = sqrtf(s) + 1.1920929e-07f;
        const int grow = row0 + lane;
        if (grow < BATCH) xn[grow] = n; else wn[grow - BATCH] = n;
    }
    __syncthreads();
    if (wid == 0)
#pragma unroll
        for (int j = 0; j < 16; ++j) {
            acc[j] += red[1][j][lane];
            red[0][j][lane] = acc[j];
        }
    __syncthreads();

    // ---- distributed epilogue: wave w owns acc slots s = w*4 .. w*4+3,
    //      holding column-block jc = (s + roff) & 15.  Near-zero dots are
    //      ballot-compacted into the global fixup queue; bit packed
    //      optimistically from the f16 sign. ----
    f32x4 facc[4];
#pragma unroll
    for (int jj = 0; jj < 4; ++jj) facc[jj] = red[0][wid * 4 + jj][lane];

#pragma unroll
    for (int jj = 0; jj < 4; ++jj) {
        const int j = (wid * 4 + jj + roff) & 15;    // actual column block
#pragma unroll
        for (int q = 0; q < 4; ++q) {
            const float v = facc[jj][q];
            const int bit = (v >= 0.0f) ? 1 : 0;
            const u64 fl = __ballot(fabsf(v) < NZ_THRESH);
            if (fl) {
                u32 base;
                if (lane == 0) base = atomicAdd(cnt, (u32)__popcll(fl));
                base = (u32)__shfl((int)base, 0, 64);
                if ((fl >> lane) & 1ull) {
                    const u32 rank = (u32)__popcll(fl & ((1ull << lane) - 1ull));
                    const u32 idx  = base + rank;
                    const u32 grow = (u32)(row0 + l4 * 4 + q);
                    const u32 col  = (u32)(j * 16 + l15);
                    if (idx < QCAP) queue[idx] = (grow << 9) | (col << 1) | (u32)bit;
                }
            }
            const u64 b = __ballot(bit != 0);
            if (l15 == 0)
                sw[l4 * 4 + q][j] = (u16)(b >> (l4 * 16));
        }
    }
    __syncthreads();
    if (t < 64) {
        const int r = t >> 2, w = t & 3;
        const u64 val = *(const u64*)&sw[r][w * 4];
        const int grow = row0 + r;
        if (grow < BATCH) cx[(size_t)grow * 4 + w] = val;
        else              cw[(size_t)(grow - BATCH) * 4 + w] = val;
    }
}

// ---------------------------------------------------------------------------
// fixup_k: whole-wave fp64 re-dot of each queued near-zero item; XOR the
// packed sign bit when the fp64 sign disagrees with the optimistic f16 bit.
// 2048 blocks x 4 waves -> ~2 items/wave; empty waves exit immediately.
// ---------------------------------------------------------------------------
__global__ __launch_bounds__(256) void fixup_k(const float* __restrict__ X,
                                               const float* __restrict__ W,
                                               const float* __restrict__ Pf,
                                               u64* __restrict__ cx,
                                               u64* __restrict__ cw,
                                               const u32* __restrict__ cnt,
                                               const u32* __restrict__ queue) {
    const int lane = threadIdx.x & 63;
    const u32 gw = blockIdx.x * 4 + (threadIdx.x >> 6);
    const u32 nw = gridDim.x * 4;
    const u32 n0 = *cnt;
    const u32 n  = (n0 < QCAP) ? n0 : QCAP;
    for (u32 it = gw; it < n; it += nw) {
        const u32 v    = queue[it];
        const u32 row  = v >> 9;
        const u32 col  = (v >> 1) & 255u;
        const u32 obit = v & 1u;
        const float* xr = ((row < BATCH) ? X + (size_t)row * INF
                                         : W + (size_t)(row - BATCH) * INF) + lane * 16;
        const float* pr = Pf + (size_t)col * INF + lane * 16;
        double s = 0.0;
#pragma unroll
        for (int c4 = 0; c4 < 4; ++c4) {
            float4 xa = *(const float4*)(xr + c4 * 4);
            float4 pa = *(const float4*)(pr + c4 * 4);
            s += (double)xa.x * pa.x + (double)xa.y * pa.y +
                 (double)xa.z * pa.z + (double)xa.w * pa.w;
        }
#pragma unroll
        for (int off = 32; off; off >>= 1) s += __shfl_xor(s, off, 64);
        const u32 nbit = (s >= 0.0) ? 1u : 0u;
        if (lane == 0 && nbit != obit) {
            u64* wptr = (row < BATCH) ? &cx[(size_t)row * 4 + (col >> 6)]
                                      : &cw[(size_t)(row - BATCH) * 4 + (col >> 6)];
            atomicXor(wptr, 1ull << (col & 63));
        }
    }
}

// ---------------------------------------------------------------------------
// out[b][m] = xn[b] * wn[m] * cos(pi * popc / 256)
// ---------------------------------------------------------------------------
__global__ __launch_bounds__(256) void popc_out(const u64* __restrict__ cx,
                                                const u64* __restrict__ cw,
                                                const float* __restrict__ xn,
                                                const float* __restrict__ wn,
                                                float* __restrict__ out) {
    __shared__ float lut[257];
    __shared__ u64 cxs[64][4];
    __shared__ float xns[64];
    const int t = threadIdx.x;

    lut[t] = (float)cos((double)t * (3.14159265358979323846 / 256.0));
    if (t == 0) lut[256] = -1.0f;

    const int r0 = blockIdx.x * 64;
    cxs[t >> 2][t & 3] = cx[(size_t)r0 * 4 + t];
    if (t < 64) xns[t] = xn[r0 + t];

    const ulonglong4* cwv4 = (const ulonglong4*)cw;
    ulonglong4 c0 = cwv4[4 * t + 0];
    ulonglong4 c1 = cwv4[4 * t + 1];
    ulonglong4 c2 = cwv4[4 * t + 2];
    ulonglong4 c3 = cwv4[4 * t + 3];
    float4 wnr = ((const float4*)wn)[t];

    __syncthreads();

    float4* outv = (float4*)out;
    const size_t obase = (size_t)r0 * (OUTF / 4) + t;
#pragma unroll 4
    for (int r = 0; r < 64; ++r) {
        const u64 a0 = cxs[r][0], a1 = cxs[r][1], a2 = cxs[r][2], a3 = cxs[r][3];
        const float sx = xns[r];
        float4 o;
        o.x = sx * wnr.x * lut[__popcll(a0 ^ c0.x) + __popcll(a1 ^ c0.y) +
                               __popcll(a2 ^ c0.z) + __popcll(a3 ^ c0.w)];
        o.y = sx * wnr.y * lut[__popcll(a0 ^ c1.x) + __popcll(a1 ^ c1.y) +
                               __popcll(a2 ^ c1.z) + __popcll(a3 ^ c1.w)];
        o.z = sx * wnr.z * lut[__popcll(a0 ^ c2.x) + __popcll(a1 ^ c2.y) +
                               __popcll(a2 ^ c2.z) + __popcll(a3 ^ c2.w)];
        o.w = sx * wnr.w * lut[__popcll(a0 ^ c3.x) + __popcll(a1 ^ c3.y) +
                               __popcll(a2 ^ c3.z) + __popcll(a3 ^ c3.w)];
        outv[obase + (size_t)r * (OUTF / 4)] = o;
    }
}

extern "C" void kernel_launch(void* const* d_in, const int* in_sizes, int n_in,
                              void* d_out, int out_size, void* d_ws, size_t ws_size,
                              hipStream_t stream) {
    const float* x = (const float*)d_in[0];
    const float* w = (const float*)d_in[1];
    const float* P = (const float*)d_in[2];
    float* out = (float*)d_out;

    char* ws = (char*)d_ws;
    f16*  Bp = (f16*)ws;                         // +0        (524288 B)
    u64*  cx = (u64*)(ws + 524288);              // +524288   (524288 B)
    u64*  cw = (u64*)(ws + 1048576);             // +1048576  (32768 B)
    float* xn = (float*)(ws + 1081344);          // +1081344  (65536 B)
    float* wn = (float*)(ws + 1146880);          // +1146880  (4096 B)
    u32*  cnt = (u32*)(ws + 1150976);            // +1150976  (256 B, 4 used)
    u32*  qu  = (u32*)(ws + 1151232);            // +1151232  (196608 B)

    prep_p<<<16, 256, 0, stream>>>(P, Bp);
    hipMemsetAsync(cnt, 0, 4, stream);

    gemm_signs<<<MTOT / 16, 256, 0, stream>>>(x, w, Bp, cx, cw, xn, wn, cnt, qu);

    fixup_k<<<2048, 256, 0, stream>>>(x, w, P, cx, cw, cnt, qu);

    popc_out<<<BATCH / 64, 256, 0, stream>>>(cx, cw, xn, wn, out);
}

// Round 8
// 61.846 us; speedup vs baseline: 4.8333x; 3.6982x over previous
//
#include <hip/hip_runtime.h>
#include <hip/hip_bf16.h>
#include <math.h>

#define BATCH 16384
#define OUTF  1024
#define INF   1024
#define KPROJ 256
#define MTOT  (BATCH + OUTF)   // 17408

#define GBM 32
#define GBN 128
#define GBK 64
#define NKT (INF / GBK)        // 16

#define NZ_THRESH 0.15f        // ~6.8 sigma of f16 dot error (sigma ~0.022)

typedef unsigned int       u32;
typedef unsigned long long u64;
typedef unsigned short     u16;
typedef _Float16           f16;
typedef __attribute__((ext_vector_type(8))) _Float16 f16x8;
typedef __attribute__((ext_vector_type(4))) float    f32x4;

#define SCHED0() __builtin_amdgcn_sched_barrier(0)

__device__ __forceinline__ void gl_lds16(const void* g, void* l) {
    __builtin_amdgcn_global_load_lds(
        (const __attribute__((address_space(1))) u32*)g,
        (__attribute__((address_space(3))) u32*)l, 16, 0, 0);
}

// ---------------------------------------------------------------------------
// prep_p: convert P (256 rows x 1024) fp32 -> f16 (RN). One wave per row.
// ---------------------------------------------------------------------------
__global__ __launch_bounds__(256) void prep_p(const float* __restrict__ P,
                                              f16* __restrict__ Bp) {
    const int wave = threadIdx.x >> 6, lane = threadIdx.x & 63;
    const int pr = blockIdx.x * 4 + wave;             // 0..255
    const float4* v = (const float4*)(P + (size_t)pr * INF);
    ushort4* d = (ushort4*)(Bp + (size_t)pr * INF);
#pragma unroll
    for (int q = 0; q < 4; ++q) {
        float4 f = v[lane + 64 * q];
        ushort4 o;
        o.x = __builtin_bit_cast(u16, (f16)f.x);
        o.y = __builtin_bit_cast(u16, (f16)f.y);
        o.z = __builtin_bit_cast(u16, (f16)f.z);
        o.w = __builtin_bit_cast(u16, (f16)f.w);
        d[lane + 64 * q] = o;
    }
}

// ---------------------------------------------------------------------------
// f16 MFMA sign GEMM, K-pipelined, with FUSED fp64 fixup and row norms.
// BM=32 x BN=128 x BK=64, 256 thr (4 waves across N, 32x32 per wave).
// EXACT R0 body (best verified: 70.0 us total).  Single change vs R0:
// XCD-aware bijective block swizzle (1088 % 8 == 0).  Default dispatch
// round-robins blockIdx across the 8 XCDs, so the two column-halves of a
// row-tile (logical ids 2m, 2m+1) land on DIFFERENT XCDs and each pulls the
// same 128 KB A-tile from HBM.  The swizzle gives each XCD a contiguous
// chunk of logical tiles: sb = (b&7)*136 + (b>>3); halves 2m,2m+1 map to
// physical b,b+8 (co-launched, same XCD) -> A-tile shared in that XCD's L2.
// ---------------------------------------------------------------------------
__global__ __launch_bounds__(256, 4) void gemm_signs(const float* __restrict__ X,
                                                     const float* __restrict__ W,
                                                     const f16* __restrict__ Bp,
                                                     const float* __restrict__ Pf,
                                                     u64* __restrict__ cx,
                                                     u64* __restrict__ cw,
                                                     float* __restrict__ xn,
                                                     float* __restrict__ wn) {
    __shared__ __align__(16) unsigned char ldsA[GBM * 8 * 16];    //  4 KB
    __shared__ __align__(16) unsigned char ldsB[GBN * 8 * 16];    // 16 KB
    __shared__ u16 sw[GBM][8];
    __shared__ float nsq[GBM][8];

    const int t    = threadIdx.x;
    const int wid  = t >> 6, lane = t & 63;
    const int l4   = lane >> 4, l15 = lane & 15;
    const int wc   = wid;                       // 4 waves across N
    // XCD-aware bijective swizzle: nwg = 1088 = 8 * 136
    const int sb   = (blockIdx.x & 7) * ((MTOT / GBM) * 2 / 8) + (blockIdx.x >> 3);
    const int bm   = sb >> 1;
    const int bn0  = (sb & 1) * GBN;
    const int am0  = bm * GBM;

    // A staging map: thread t -> chunk ca of row ra, written at linear slot t
    const int ra = t >> 3, sa = t & 7, ca = sa ^ (ra & 7);
    const float* Asrc = (am0 < BATCH) ? X + (size_t)am0 * INF
                                      : W + (size_t)(am0 - BATCH) * INF;
    const float* aRow = Asrc + (size_t)ra * INF + ca * 8;

    // B staging map (global_load_lds): wave wid, rep i covers linear chunks
    const f16* bsrc[4];
#pragma unroll
    for (int i = 0; i < 4; ++i) {
        const int g = (i * 4 + wid) * 64 + lane;
        const int row = g >> 3, sl = g & 7, cb = sl ^ (row & 7);
        bsrc[i] = Bp + (size_t)(bn0 + row) * INF + cb * 8;
    }

    f32x4 acc[2][2] = {};
    float ssq = 0.0f;
    float4 pf0 = *(const float4*)(aRow);
    float4 pf1 = *(const float4*)(aRow + 4);

    for (int kt = 0; kt < NKT; ++kt) {
        // ---- STAGE ----
        ssq += pf0.x * pf0.x + pf0.y * pf0.y + pf0.z * pf0.z + pf0.w * pf0.w +
               pf1.x * pf1.x + pf1.y * pf1.y + pf1.z * pf1.z + pf1.w * pf1.w;
        {
            f16x8 h;
            h[0] = (f16)pf0.x; h[1] = (f16)pf0.y; h[2] = (f16)pf0.z; h[3] = (f16)pf0.w;
            h[4] = (f16)pf1.x; h[5] = (f16)pf1.y; h[6] = (f16)pf1.z; h[7] = (f16)pf1.w;
            *(f16x8*)(ldsA + t * 16) = h;
        }
#pragma unroll
        for (int i = 0; i < 4; ++i)
            gl_lds16(bsrc[i] + kt * GBK, ldsB + (i * 4 + wid) * 1024);
        SCHED0();
        if (kt + 1 < NKT) {   // A prefetch for kt+1 stays in flight across barrier
            pf0 = *(const float4*)(aRow + (kt + 1) * GBK);
            pf1 = *(const float4*)(aRow + (kt + 1) * GBK + 4);
            SCHED0();
            asm volatile("s_waitcnt vmcnt(2) lgkmcnt(0)" ::: "memory");
        } else {
            asm volatile("s_waitcnt vmcnt(0) lgkmcnt(0)" ::: "memory");
        }
        SCHED0();
        __builtin_amdgcn_s_barrier();
        SCHED0();
        // ---- COMPUTE ----
#pragma unroll
        for (int ks = 0; ks < 2; ++ks) {
            f16x8 af[2], bf[2];
#pragma unroll
            for (int i = 0; i < 2; ++i) {
                const int row = i * 16 + l15;
                const int slot = (ks * 4 + l4) ^ (row & 7);
                af[i] = *(const f16x8*)(ldsA + row * 128 + slot * 16);
            }
#pragma unroll
            for (int j = 0; j < 2; ++j) {
                const int col = wc * 32 + j * 16 + l15;
                const int slot = (ks * 4 + l4) ^ (col & 7);
                bf[j] = *(const f16x8*)(ldsB + col * 128 + slot * 16);
            }
#pragma unroll
            for (int i = 0; i < 2; ++i)
#pragma unroll
                for (int j = 0; j < 2; ++j)
                    acc[i][j] = __builtin_amdgcn_mfma_f32_16x16x32_f16(af[i], bf[j], acc[i][j], 0, 0, 0);
        }
        SCHED0();
        __builtin_amdgcn_s_barrier();
        SCHED0();
    }

    nsq[ra][sa] = ssq;

    // epilogue: fused fp64 fixup for near-zero dots, then ballot sign-pack.
    // C layout: local row = i*16 + l4*4 + q, col = bn0 + wc*32 + j*16 + l15.
#pragma unroll
    for (int i = 0; i < 2; ++i)
#pragma unroll
        for (int j = 0; j < 2; ++j)
#pragma unroll
            for (int q = 0; q < 4; ++q) {
                const float v = acc[i][j][q];
                int bit = (v >= 0.0f) ? 1 : 0;
                u64 fl = __ballot(fabsf(v) < NZ_THRESH);
                while (fl) {   // rare (~4/wave): whole wave re-dots in fp64
                    const int src = __ffsll((long long)fl) - 1;
                    fl &= fl - 1;
                    const int lrow = i * 16 + ((src >> 4) << 2) + q;
                    const int col  = bn0 + wc * 32 + j * 16 + (src & 15);
                    const float* xr = Asrc + (size_t)lrow * INF + lane * 16;
                    const float* pr = Pf + (size_t)col * INF + lane * 16;
                    double s = 0.0;
#pragma unroll
                    for (int c4 = 0; c4 < 4; ++c4) {
                        float4 xa = *(const float4*)(xr + c4 * 4);
                        float4 pa = *(const float4*)(pr + c4 * 4);
                        s += (double)xa.x * pa.x + (double)xa.y * pa.y +
                             (double)xa.z * pa.z + (double)xa.w * pa.w;
                    }
#pragma unroll
                    for (int off = 32; off; off >>= 1) s += __shfl_xor(s, off, 64);
                    if (lane == src) bit = (s >= 0.0) ? 1 : 0;
                }
                const u64 b = __ballot(bit != 0);
                if (l15 == 0)
                    sw[i * 16 + l4 * 4 + q][wc * 2 + j] = (u16)(b >> (l4 * 16));
            }
    if (bn0 == 0 && t < GBM) {   // fused norm write (one block-column only)
        const float* p = nsq[t];
        float s = ((p[0] + p[1]) + (p[2] + p[3])) + ((p[4] + p[5]) + (p[6] + p[7]));
        const float n = sqrtf(s) + 1.1920929e-07f;
        const int grow = am0 + t;
        if (grow < BATCH) xn[grow] = n; else wn[grow - BATCH] = n;
    }
    __syncthreads();
    if (t < 64) {
        const int r = t >> 1, wsel = t & 1;
        const u64 val = *(const u64*)&sw[r][wsel * 4];
        const int grow = am0 + r;
        const int word = (sb & 1) * 2 + wsel;
        if (grow < BATCH) cx[(size_t)grow * 4 + word] = val;
        else              cw[(size_t)(grow - BATCH) * 4 + word] = val;
    }
}

// ---------------------------------------------------------------------------
// out[b][m] = xn[b] * wn[m] * cos(pi * popc / 256)
// ---------------------------------------------------------------------------
__global__ __launch_bounds__(256) void popc_out(const u64* __restrict__ cx,
                                                const u64* __restrict__ cw,
                                                const float* __restrict__ xn,
                                                const float* __restrict__ wn,
                                                float* __restrict__ out) {
    __shared__ float lut[257];
    __shared__ u64 cxs[64][4];
    __shared__ float xns[64];
    const int t = threadIdx.x;

    lut[t] = (float)cos((double)t * (3.14159265358979323846 / 256.0));
    if (t == 0) lut[256] = -1.0f;

    const int r0 = blockIdx.x * 64;
    cxs[t >> 2][t & 3] = cx[(size_t)r0 * 4 + t];
    if (t < 64) xns[t] = xn[r0 + t];

    const ulonglong4* cwv4 = (const ulonglong4*)cw;
    ulonglong4 c0 = cwv4[4 * t + 0];
    ulonglong4 c1 = cwv4[4 * t + 1];
    ulonglong4 c2 = cwv4[4 * t + 2];
    ulonglong4 c3 = cwv4[4 * t + 3];
    float4 wnr = ((const float4*)wn)[t];

    __syncthreads();

    float4* outv = (float4*)out;
    const size_t obase = (size_t)r0 * (OUTF / 4) + t;
#pragma unroll 4
    for (int r = 0; r < 64; ++r) {
        const u64 a0 = cxs[r][0], a1 = cxs[r][1], a2 = cxs[r][2], a3 = cxs[r][3];
        const float sx = xns[r];
        float4 o;
        o.x = sx * wnr.x * lut[__popcll(a0 ^ c0.x) + __popcll(a1 ^ c0.y) +
                               __popcll(a2 ^ c0.z) + __popcll(a3 ^ c0.w)];
        o.y = sx * wnr.y * lut[__popcll(a0 ^ c1.x) + __popcll(a1 ^ c1.y) +
                               __popcll(a2 ^ c1.z) + __popcll(a3 ^ c1.w)];
        o.z = sx * wnr.z * lut[__popcll(a0 ^ c2.x) + __popcll(a1 ^ c2.y) +
                               __popcll(a2 ^ c2.z) + __popcll(a3 ^ c2.w)];
        o.w = sx * wnr.w * lut[__popcll(a0 ^ c3.x) + __popcll(a1 ^ c3.y) +
                               __popcll(a2 ^ c3.z) + __popcll(a3 ^ c3.w)];
        outv[obase + (size_t)r * (OUTF / 4)] = o;
    }
}

extern "C" void kernel_launch(void* const* d_in, const int* in_sizes, int n_in,
                              void* d_out, int out_size, void* d_ws, size_t ws_size,
                              hipStream_t stream) {
    const float* x = (const float*)d_in[0];
    const float* w = (const float*)d_in[1];
    const float* P = (const float*)d_in[2];
    float* out = (float*)d_out;

    char* ws = (char*)d_ws;
    f16*  Bp = (f16*)ws;                         // +0        (524288 B)
    u64*  cx = (u64*)(ws + 524288);              // +524288   (524288 B)
    u64*  cw = (u64*)(ws + 1048576);             // +1048576  (32768 B)
    float* xn = (float*)(ws + 1081344);          // +1081344  (65536 B)
    float* wn = (float*)(ws + 1146880);          // +1146880  (4096 B)

    prep_p<<<KPROJ / 4, 256, 0, stream>>>(P, Bp);

    gemm_signs<<<(MTOT / GBM) * 2, 256, 0, stream>>>(x, w, Bp, P, cx, cw, xn, wn);

    popc_out<<<BATCH / 64, 256, 0, stream>>>(cx, cw, xn, wn, out);
}

// Round 9
// 61.684 us; speedup vs baseline: 4.8460x; 1.0026x over previous
//
#include <hip/hip_runtime.h>
#include <hip/hip_bf16.h>
#include <math.h>

#define BATCH 16384
#define OUTF  1024
#define INF   1024
#define KPROJ 256
#define MTOT  (BATCH + OUTF)   // 17408

#define GBM 64
#define GBN 128
#define GBK 64
#define NKT (INF / GBK)        // 16
#define NWG ((MTOT / GBM) * 2) // 544 blocks (544 % 8 == 0)

#define NZ_THRESH 0.15f        // ~6.8 sigma of f16 dot error (sigma ~0.022)

typedef unsigned int       u32;
typedef unsigned long long u64;
typedef unsigned short     u16;
typedef _Float16           f16;
typedef __attribute__((ext_vector_type(8))) _Float16 f16x8;
typedef __attribute__((ext_vector_type(4))) float    f32x4;

#define SCHED0() __builtin_amdgcn_sched_barrier(0)

__device__ __forceinline__ void gl_lds16(const void* g, void* l) {
    __builtin_amdgcn_global_load_lds(
        (const __attribute__((address_space(1))) u32*)g,
        (__attribute__((address_space(3))) u32*)l, 16, 0, 0);
}

// ---------------------------------------------------------------------------
// prep_p: convert P (256 rows x 1024) fp32 -> f16 (RN). One wave per row.
// ---------------------------------------------------------------------------
__global__ __launch_bounds__(256) void prep_p(const float* __restrict__ P,
                                              f16* __restrict__ Bp) {
    const int wave = threadIdx.x >> 6, lane = threadIdx.x & 63;
    const int pr = blockIdx.x * 4 + wave;             // 0..255
    const float4* v = (const float4*)(P + (size_t)pr * INF);
    ushort4* d = (ushort4*)(Bp + (size_t)pr * INF);
#pragma unroll
    for (int q = 0; q < 4; ++q) {
        float4 f = v[lane + 64 * q];
        ushort4 o;
        o.x = __builtin_bit_cast(u16, (f16)f.x);
        o.y = __builtin_bit_cast(u16, (f16)f.y);
        o.z = __builtin_bit_cast(u16, (f16)f.z);
        o.w = __builtin_bit_cast(u16, (f16)f.w);
        d[lane + 64 * q] = o;
    }
}

// ---------------------------------------------------------------------------
// f16 MFMA sign GEMM: R8's verified schedule skeleton (2-barrier K-loop,
// global_load_lds B staging, A reg-prefetch kept in flight across the
// barrier via counted vmcnt, XCD-aware bijective swizzle) with GBM doubled
// 32 -> 64.  Halves block count (1088 -> 544), halves B L2-read traffic
// (557 -> 278 MB), doubles MFMA per barrier-pair (8 -> 16 per wave).
// Per K-step per thread vmem queue: [4x gl_lds B, 4x A float4] ->
// s_waitcnt vmcnt(4) drains B, keeps the A prefetch in flight.
// LDS ~27 KB, VGPR ~80: still 4 blocks/CU under __launch_bounds__(256,4).
// ---------------------------------------------------------------------------
__global__ __launch_bounds__(256, 4) void gemm_signs(const float* __restrict__ X,
                                                     const float* __restrict__ W,
                                                     const f16* __restrict__ Bp,
                                                     const float* __restrict__ Pf,
                                                     u64* __restrict__ cx,
                                                     u64* __restrict__ cw,
                                                     float* __restrict__ xn,
                                                     float* __restrict__ wn) {
    __shared__ __align__(16) unsigned char ldsA[GBM * 8 * 16];    //  8 KB
    __shared__ __align__(16) unsigned char ldsB[GBN * 8 * 16];    // 16 KB
    __shared__ u16 sw[GBM][8];
    __shared__ float nsq[GBM][8];

    const int t    = threadIdx.x;
    const int wid  = t >> 6, lane = t & 63;
    const int l4   = lane >> 4, l15 = lane & 15;
    const int wc   = wid;                       // 4 waves across N
    // XCD-aware bijective swizzle: NWG = 544 = 8 * 68; column halves
    // sb=2m,2m+1 map to physical b,b+8 (same XCD chunk -> shared A in L2)
    const int sb   = (blockIdx.x & 7) * (NWG / 8) + (blockIdx.x >> 3);
    const int bm   = sb >> 1;
    const int bn0  = (sb & 1) * GBN;
    const int am0  = bm * GBM;

    // A staging map: thread t -> chunk ca of rows ra and ra+32 (same &7 ->
    // same swizzled chunk), written at linear slots t and t+256.
    const int ra = t >> 3, sa = t & 7, ca = sa ^ (ra & 7);
    const float* Asrc = (am0 < BATCH) ? X + (size_t)am0 * INF
                                      : W + (size_t)(am0 - BATCH) * INF;
    const float* aRow0 = Asrc + (size_t)ra * INF + ca * 8;
    const float* aRow1 = aRow0 + (size_t)32 * INF;

    // B staging map (global_load_lds): wave wid, rep i covers linear chunks
    const f16* bsrc[4];
#pragma unroll
    for (int i = 0; i < 4; ++i) {
        const int g = (i * 4 + wid) * 64 + lane;
        const int row = g >> 3, sl = g & 7, cb = sl ^ (row & 7);
        bsrc[i] = Bp + (size_t)(bn0 + row) * INF + cb * 8;
    }

    f32x4 acc[4][2] = {};
    float ssq0 = 0.0f, ssq1 = 0.0f;
    float4 pf0 = *(const float4*)(aRow0);
    float4 pf1 = *(const float4*)(aRow0 + 4);
    float4 pf2 = *(const float4*)(aRow1);
    float4 pf3 = *(const float4*)(aRow1 + 4);

    for (int kt = 0; kt < NKT; ++kt) {
        // ---- STAGE ----
        ssq0 += pf0.x * pf0.x + pf0.y * pf0.y + pf0.z * pf0.z + pf0.w * pf0.w +
                pf1.x * pf1.x + pf1.y * pf1.y + pf1.z * pf1.z + pf1.w * pf1.w;
        ssq1 += pf2.x * pf2.x + pf2.y * pf2.y + pf2.z * pf2.z + pf2.w * pf2.w +
                pf3.x * pf3.x + pf3.y * pf3.y + pf3.z * pf3.z + pf3.w * pf3.w;
        {
            f16x8 h0, h1;
            h0[0] = (f16)pf0.x; h0[1] = (f16)pf0.y; h0[2] = (f16)pf0.z; h0[3] = (f16)pf0.w;
            h0[4] = (f16)pf1.x; h0[5] = (f16)pf1.y; h0[6] = (f16)pf1.z; h0[7] = (f16)pf1.w;
            h1[0] = (f16)pf2.x; h1[1] = (f16)pf2.y; h1[2] = (f16)pf2.z; h1[3] = (f16)pf2.w;
            h1[4] = (f16)pf3.x; h1[5] = (f16)pf3.y; h1[6] = (f16)pf3.z; h1[7] = (f16)pf3.w;
            *(f16x8*)(ldsA + t * 16) = h0;
            *(f16x8*)(ldsA + 4096 + t * 16) = h1;
        }
#pragma unroll
        for (int i = 0; i < 4; ++i)
            gl_lds16(bsrc[i] + kt * GBK, ldsB + (i * 4 + wid) * 1024);
        SCHED0();
        if (kt + 1 < NKT) {   // A prefetch for kt+1 stays in flight across barrier
            pf0 = *(const float4*)(aRow0 + (kt + 1) * GBK);
            pf1 = *(const float4*)(aRow0 + (kt + 1) * GBK + 4);
            pf2 = *(const float4*)(aRow1 + (kt + 1) * GBK);
            pf3 = *(const float4*)(aRow1 + (kt + 1) * GBK + 4);
            SCHED0();
            asm volatile("s_waitcnt vmcnt(4) lgkmcnt(0)" ::: "memory");
        } else {
            asm volatile("s_waitcnt vmcnt(0) lgkmcnt(0)" ::: "memory");
        }
        SCHED0();
        __builtin_amdgcn_s_barrier();
        SCHED0();
        // ---- COMPUTE ----
#pragma unroll
        for (int ks = 0; ks < 2; ++ks) {
            f16x8 af[4], bf[2];
#pragma unroll
            for (int i = 0; i < 4; ++i) {
                const int row = i * 16 + l15;
                const int slot = (ks * 4 + l4) ^ (row & 7);
                af[i] = *(const f16x8*)(ldsA + row * 128 + slot * 16);
            }
#pragma unroll
            for (int j = 0; j < 2; ++j) {
                const int col = wc * 32 + j * 16 + l15;
                const int slot = (ks * 4 + l4) ^ (col & 7);
                bf[j] = *(const f16x8*)(ldsB + col * 128 + slot * 16);
            }
#pragma unroll
            for (int i = 0; i < 4; ++i)
#pragma unroll
                for (int j = 0; j < 2; ++j)
                    acc[i][j] = __builtin_amdgcn_mfma_f32_16x16x32_f16(af[i], bf[j], acc[i][j], 0, 0, 0);
        }
        SCHED0();
        __builtin_amdgcn_s_barrier();
        SCHED0();
    }

    nsq[ra][sa]      = ssq0;
    nsq[ra + 32][sa] = ssq1;

    // epilogue: fused fp64 fixup for near-zero dots, then ballot sign-pack.
    // C layout: local row = i*16 + l4*4 + q, col = bn0 + wc*32 + j*16 + l15.
#pragma unroll
    for (int i = 0; i < 4; ++i)
#pragma unroll
        for (int j = 0; j < 2; ++j)
#pragma unroll
            for (int q = 0; q < 4; ++q) {
                const float v = acc[i][j][q];
                int bit = (v >= 0.0f) ? 1 : 0;
                u64 fl = __ballot(fabsf(v) < NZ_THRESH);
                while (fl) {   // rare (~8/wave): whole wave re-dots in fp64
                    const int src = __ffsll((long long)fl) - 1;
                    fl &= fl - 1;
                    const int lrow = i * 16 + ((src >> 4) << 2) + q;
                    const int col  = bn0 + wc * 32 + j * 16 + (src & 15);
                    const float* xr = Asrc + (size_t)lrow * INF + lane * 16;
                    const float* pr = Pf + (size_t)col * INF + lane * 16;
                    double s = 0.0;
#pragma unroll
                    for (int c4 = 0; c4 < 4; ++c4) {
                        float4 xa = *(const float4*)(xr + c4 * 4);
                        float4 pa = *(const float4*)(pr + c4 * 4);
                        s += (double)xa.x * pa.x + (double)xa.y * pa.y +
                             (double)xa.z * pa.z + (double)xa.w * pa.w;
                    }
#pragma unroll
                    for (int off = 32; off; off >>= 1) s += __shfl_xor(s, off, 64);
                    if (lane == src) bit = (s >= 0.0) ? 1 : 0;
                }
                const u64 b = __ballot(bit != 0);
                if (l15 == 0)
                    sw[i * 16 + l4 * 4 + q][wc * 2 + j] = (u16)(b >> (l4 * 16));
            }
    if (bn0 == 0 && t < GBM) {   // fused norm write (one block-column only)
        const float* p = nsq[t];
        float s = ((p[0] + p[1]) + (p[2] + p[3])) + ((p[4] + p[5]) + (p[6] + p[7]));
        const float n = sqrtf(s) + 1.1920929e-07f;
        const int grow = am0 + t;
        if (grow < BATCH) xn[grow] = n; else wn[grow - BATCH] = n;
    }
    __syncthreads();
    if (t < 128) {
        const int r = t >> 1, wsel = t & 1;
        const u64 val = *(const u64*)&sw[r][wsel * 4];
        const int grow = am0 + r;
        const int word = (sb & 1) * 2 + wsel;
        if (grow < BATCH) cx[(size_t)grow * 4 + word] = val;
        else              cw[(size_t)(grow - BATCH) * 4 + word] = val;
    }
}

// ---------------------------------------------------------------------------
// out[b][m] = xn[b] * wn[m] * cos(pi * popc / 256)
// ---------------------------------------------------------------------------
__global__ __launch_bounds__(256) void popc_out(const u64* __restrict__ cx,
                                                const u64* __restrict__ cw,
                                                const float* __restrict__ xn,
                                                const float* __restrict__ wn,
                                                float* __restrict__ out) {
    __shared__ float lut[257];
    __shared__ u64 cxs[64][4];
    __shared__ float xns[64];
    const int t = threadIdx.x;

    lut[t] = (float)cos((double)t * (3.14159265358979323846 / 256.0));
    if (t == 0) lut[256] = -1.0f;

    const int r0 = blockIdx.x * 64;
    cxs[t >> 2][t & 3] = cx[(size_t)r0 * 4 + t];
    if (t < 64) xns[t] = xn[r0 + t];

    const ulonglong4* cwv4 = (const ulonglong4*)cw;
    ulonglong4 c0 = cwv4[4 * t + 0];
    ulonglong4 c1 = cwv4[4 * t + 1];
    ulonglong4 c2 = cwv4[4 * t + 2];
    ulonglong4 c3 = cwv4[4 * t + 3];
    float4 wnr = ((const float4*)wn)[t];

    __syncthreads();

    float4* outv = (float4*)out;
    const size_t obase = (size_t)r0 * (OUTF / 4) + t;
#pragma unroll 4
    for (int r = 0; r < 64; ++r) {
        const u64 a0 = cxs[r][0], a1 = cxs[r][1], a2 = cxs[r][2], a3 = cxs[r][3];
        const float sx = xns[r];
        float4 o;
        o.x = sx * wnr.x * lut[__popcll(a0 ^ c0.x) + __popcll(a1 ^ c0.y) +
                               __popcll(a2 ^ c0.z) + __popcll(a3 ^ c0.w)];
        o.y = sx * wnr.y * lut[__popcll(a0 ^ c1.x) + __popcll(a1 ^ c1.y) +
                               __popcll(a2 ^ c1.z) + __popcll(a3 ^ c1.w)];
        o.z = sx * wnr.z * lut[__popcll(a0 ^ c2.x) + __popcll(a1 ^ c2.y) +
                               __popcll(a2 ^ c2.z) + __popcll(a3 ^ c2.w)];
        o.w = sx * wnr.w * lut[__popcll(a0 ^ c3.x) + __popcll(a1 ^ c3.y) +
                               __popcll(a2 ^ c3.z) + __popcll(a3 ^ c3.w)];
        outv[obase + (size_t)r * (OUTF / 4)] = o;
    }
}

extern "C" void kernel_launch(void* const* d_in, const int* in_sizes, int n_in,
                              void* d_out, int out_size, void* d_ws, size_t ws_size,
                              hipStream_t stream) {
    const float* x = (const float*)d_in[0];
    const float* w = (const float*)d_in[1];
    const float* P = (const float*)d_in[2];
    float* out = (float*)d_out;

    char* ws = (char*)d_ws;
    f16*  Bp = (f16*)ws;                         // +0        (524288 B)
    u64*  cx = (u64*)(ws + 524288);              // +524288   (524288 B)
    u64*  cw = (u64*)(ws + 1048576);             // +1048576  (32768 B)
    float* xn = (float*)(ws + 1081344);          // +1081344  (65536 B)
    float* wn = (float*)(ws + 1146880);          // +1146880  (4096 B)

    prep_p<<<KPROJ / 4, 256, 0, stream>>>(P, Bp);

    gemm_signs<<<NWG, 256, 0, stream>>>(x, w, Bp, P, cx, cw, xn, wn);

    popc_out<<<BATCH / 64, 256, 0, stream>>>(cx, cw, xn, wn, out);
}